// Round 11
// baseline (428.983 us; speedup 1.0000x reference)
//
#include <hip/hip_runtime.h>
#include <hip/hip_bf16.h>

// Problem constants (fixed by reference)
#define NCELLS 16384
#define DIM    768
#define NHEADS 8
#define DHEAD  96           // 768/8
#define MAXH   8
#define ND     (NCELLS * DIM)          // 12582912

// ALL float tensors are fp32 I/O (reference uses jnp.float32 throughout).
// Internal compute: bf16 operands + MFMA, fp32 accumulate/output.

using bf16 = __hip_bfloat16;
typedef short  short8  __attribute__((ext_vector_type(8)));
typedef short  short4v __attribute__((ext_vector_type(4)));
typedef float  floatx4 __attribute__((ext_vector_type(4)));

__device__ inline short f2b(float f) {
    bf16 h = __float2bfloat16(f);
    unsigned short u; __builtin_memcpy(&u, &h, 2); return (short)u;
}
__device__ inline float b2f(short u) {
    unsigned x = ((unsigned)(unsigned short)u) << 16;
    float f; __builtin_memcpy(&f, &x, 4); return f;
}

// load 8 consecutive fp32, convert to 8 bf16
__device__ inline short8 ld8(const float* p) {
    floatx4 a = *reinterpret_cast<const floatx4*>(p);
    floatx4 b = *reinterpret_cast<const floatx4*>(p + 4);
    short8 o;
#pragma unroll
    for (int i = 0; i < 4; ++i) { o[i] = f2b(a[i]); o[i + 4] = f2b(b[i]); }
    return o;
}

// async 16B global -> LDS (direct DMA, no VGPR round-trip).
__device__ __forceinline__ void cp16(const void* g, void* l) {
    __builtin_amdgcn_global_load_lds(
        (const __attribute__((address_space(1))) void*)g,
        (__attribute__((address_space(3))) void*)l, 16, 0, 0);
}

// ===========================================================================
// Pure-bf16 GEMM, 128x128 tile, BK=64, 256 thr (4 waves, 2x2), staging via
// global_load_lds width=16 (m97 structure; verified R8). Used for Q-proj.
// ===========================================================================
template <int DUAL, int COUT>
__global__ __launch_bounds__(256) void gemm_bf(
    const bf16* __restrict__ A, const bf16* __restrict__ A2,
    const bf16* __restrict__ W, int ldw,
    const float* __restrict__ bias,
    float* __restrict__ Cf, bf16* __restrict__ Cb, int K)
{
    __shared__ short As[128 * 64];   // 16,384 B
    __shared__ short Bs[128 * 64];   // 16,384 B
    const int tid = threadIdx.x, wave = tid >> 6, lane = tid & 63;
    const int id = blockIdx.x;
    const int m0 = (id & 127) * 128;
    const int n0 = (id >> 7) * 128;
    const int wr = (wave & 1) * 64, wc = (wave >> 1) * 64;
    const int fr = lane & 15, kg = lane >> 4;

    const int srow = lane >> 3;            // row within chunk (== row&7)
    const int scol = (lane & 7) ^ srow;    // swizzled source k-group

    floatx4 acc[16];
#pragma unroll
    for (int i = 0; i < 16; ++i) acc[i] = (floatx4){0.f, 0.f, 0.f, 0.f};

    for (int k0 = 0; k0 < K; k0 += 64) {
        const bf16* Ak; int ka;
        if (!DUAL || k0 < DIM) { Ak = A;  ka = k0; }
        else                   { Ak = A2; ka = k0 - DIM; }

        __syncthreads();
#pragma unroll
        for (int i = 0; i < 4; ++i) {
            const int c = i * 4 + wave;
            const int row = c * 8 + srow;
            cp16(Ak + (size_t)(m0 + row) * DIM + ka + scol * 8,
                 &As[c * 512 + lane * 8]);
            cp16(W  + (size_t)(n0 + row) * ldw + k0 + scol * 8,
                 &Bs[c * 512 + lane * 8]);
        }
        __syncthreads();

#pragma unroll
        for (int kk = 0; kk < 2; ++kk) {
            short8 af[4], bfv[4];
#pragma unroll
            for (int i = 0; i < 4; ++i) {
                const int sa = ((kk * 4 + kg) ^ (fr & 7)) * 8;
                af[i]  = *reinterpret_cast<const short8*>(&As[(wr + i * 16 + fr) * 64 + sa]);
                bfv[i] = *reinterpret_cast<const short8*>(&Bs[(wc + i * 16 + fr) * 64 + sa]);
            }
#pragma unroll
            for (int i = 0; i < 4; ++i)
#pragma unroll
                for (int j = 0; j < 4; ++j)
                    acc[i * 4 + j] = __builtin_amdgcn_mfma_f32_16x16x32_bf16(
                        af[i], bfv[j], acc[i * 4 + j], 0, 0, 0);
        }
    }

    const int col_l = lane & 15, row_q = kg * 4;
#pragma unroll
    for (int j = 0; j < 4; ++j) {
        const int col = n0 + wc + j * 16 + col_l;
        const float bv = bias[col];
#pragma unroll
        for (int i = 0; i < 4; ++i) {
#pragma unroll
            for (int r = 0; r < 4; ++r) {
                const int row = m0 + wr + i * 16 + row_q + r;
                const float v = acc[i * 4 + j][r] + bv;
                if (COUT == 0) Cf[(size_t)row * DIM + col] = v;
                else           Cb[(size_t)row * DIM + col] = __float2bfloat16(v);
            }
        }
    }
}

// ===========================================================================
// R10 fusion GEMM + LayerNorm + ReLU + select, single dispatch with the
// PROVEN hand-rolled grid barrier (R10 passed correctness; only flaw was
// 145us from the compiler spilling acc across the barrier: VGPR_Count=64
// with 64 VGPRs of live acc -> everything in scratch, MfmaUtil 10.9%).
// FIX: do NOT keep acc live across the barrier.
//   phase 1 = exactly R8's verified epilogue (bias + fp32 h store to out,
//             ~84 VGPR, 53us pattern) + R10's proven stats reduction -> Sg.
//   barrier = R10's proven counter + acquire-spin (co-residency guaranteed:
//             __launch_bounds__(256,3), grid 768 = 3 x 256 CUs, LDS 36KB).
//   phase 2 = re-read own 64KB h tile (L2/L3-resident, not HBM), LN+ReLU+
//             has-select in ln_v-style coalesced 2-thr/row pattern, store.
// Deletes the ln dispatch and its 48MB HBM h-read; register live ranges end
// before the barrier -> no spill.
// ===========================================================================
__global__ __launch_bounds__(256, 3) void fusion_ln_sync(
    const bf16* __restrict__ A, const bf16* __restrict__ A2,
    const bf16* __restrict__ W,
    const float* __restrict__ bias, float* __restrict__ out,
    float* __restrict__ Sg,                    // [128 mt][128 row][6 nt] float2
    int* __restrict__ ctr,
    const int* __restrict__ map,
    const float* __restrict__ ce, const int* __restrict__ pos,
    const float* __restrict__ re, const float* __restrict__ co,
    const float* __restrict__ g, const float* __restrict__ b)
{
    __shared__ short As[128 * 64];
    __shared__ short Bs[128 * 64];
    __shared__ float rs[128][2], rq2[128][2];
    __shared__ float muL[128], invL[128];
    __shared__ int   hasL[128];

    const int tid = threadIdx.x, wave = tid >> 6, lane = tid & 63;
    const int id = blockIdx.x;
    const int mt = id & 127, nt = id >> 7;     // 128 m-tiles x 6 n-tiles
    const int m0 = mt * 128, n0 = nt * 128;
    const int wr = (wave & 1) * 64, wc = (wave >> 1) * 64;
    const int fr = lane & 15, kg = lane >> 4;
    const int srow = lane >> 3;
    const int scol = (lane & 7) ^ srow;

    floatx4 acc[16];
#pragma unroll
    for (int i = 0; i < 16; ++i) acc[i] = (floatx4){0.f, 0.f, 0.f, 0.f};

    for (int k0 = 0; k0 < 1536; k0 += 64) {
        const bf16* Ak; int ka;
        if (k0 < DIM) { Ak = A;  ka = k0; }
        else          { Ak = A2; ka = k0 - DIM; }

        __syncthreads();
#pragma unroll
        for (int i = 0; i < 4; ++i) {
            const int c = i * 4 + wave;
            const int row = c * 8 + srow;
            cp16(Ak + (size_t)(m0 + row) * DIM + ka + scol * 8,
                 &As[c * 512 + lane * 8]);
            cp16(W  + (size_t)(n0 + row) * 1536 + k0 + scol * 8,
                 &Bs[c * 512 + lane * 8]);
        }
        __syncthreads();

#pragma unroll
        for (int kk = 0; kk < 2; ++kk) {
            short8 af[4], bfv[4];
#pragma unroll
            for (int i = 0; i < 4; ++i) {
                const int sa = ((kk * 4 + kg) ^ (fr & 7)) * 8;
                af[i]  = *reinterpret_cast<const short8*>(&As[(wr + i * 16 + fr) * 64 + sa]);
                bfv[i] = *reinterpret_cast<const short8*>(&Bs[(wc + i * 16 + fr) * 64 + sa]);
            }
#pragma unroll
            for (int i = 0; i < 4; ++i)
#pragma unroll
                for (int j = 0; j < 4; ++j)
                    acc[i * 4 + j] = __builtin_amdgcn_mfma_f32_16x16x32_bf16(
                        af[i], bfv[j], acc[i * 4 + j], 0, 0, 0);
        }
    }

    // ---- phase 1: R8 epilogue (bias + h store) + per-row partials -> Sg ----
    const int col_l = lane & 15, row_q = kg * 4;
    float bcov[4];
#pragma unroll
    for (int j = 0; j < 4; ++j) bcov[j] = bias[n0 + wc + j * 16 + col_l];

#pragma unroll
    for (int i = 0; i < 4; ++i) {
#pragma unroll
        for (int r = 0; r < 4; ++r) {
            const int rowl = wr + i * 16 + row_q + r;
            float s = 0.f, q = 0.f;
#pragma unroll
            for (int j = 0; j < 4; ++j) {
                const int col = n0 + wc + j * 16 + col_l;
                const float v = acc[i * 4 + j][r] + bcov[j];
                out[(size_t)(m0 + rowl) * DIM + col] = v;
                s += v; q += v * v;
            }
            // reduce over the 16 col_l lanes (xor 1,2,4,8 stays in kg group)
#pragma unroll
            for (int off = 1; off < 16; off <<= 1) {
                s += __shfl_xor(s, off);
                q += __shfl_xor(q, off);
            }
            if (col_l == 0) { rs[rowl][wc >> 6] = s; rq2[rowl][wc >> 6] = q; }
        }
    }
    __syncthreads();
    if (tid < 128) {
        const float s = rs[tid][0] + rs[tid][1];
        const float q = rq2[tid][0] + rq2[tid][1];
        float2* Sp = (float2*)Sg + ((size_t)mt * 128 + tid) * 6 + nt;
        *Sp = make_float2(s, q);
    }

    // ---- grid barrier (all 768 blocks co-resident; proven R10) ----
    __syncthreads();                 // all Sg stores issued
    __threadfence();                 // device-scope visibility of Sg + h
    if (tid == 0) {
        __hip_atomic_fetch_add(ctr, 1, __ATOMIC_ACQ_REL, __HIP_MEMORY_SCOPE_AGENT);
        while (__hip_atomic_load(ctr, __ATOMIC_ACQUIRE, __HIP_MEMORY_SCOPE_AGENT)
               < (int)gridDim.x) { __builtin_amdgcn_s_sleep(8); }
    }
    __syncthreads();                 // tid0's acquire ordered before reads

    // ---- phase 2: row stats from Sg; LN+ReLU+select on own h tile ----
    if (tid < 128) {
        const float2* Sp = (const float2*)Sg + ((size_t)mt * 128 + tid) * 6;
        float s = 0.f, q = 0.f;
#pragma unroll
        for (int k = 0; k < 6; ++k) { float2 v = Sp[k]; s += v.x; q += v.y; }
        const float mu  = s * (1.f / 768.f);
        const float var = q * (1.f / 768.f) - mu * mu;
        muL[tid]  = mu;
        invL[tid] = rsqrtf(var + 1e-5f);
        int hb = 0;
#pragma unroll
        for (int sl = 0; sl < MAXH; ++sl)
            if (map[(size_t)(m0 + tid) * MAXH + sl] >= 0) hb = 1;
        hasL[tid] = hb;
    }
    __syncthreads();

    // 2 threads per row x 128 rows; each handles 64 contiguous cols (16 x f4).
    // h re-read is from the block's OWN just-written tile: L2/L3-hot.
    {
        const int rowl = tid >> 1;
        const int ch   = (tid & 1) * 64;
        const int grow = m0 + rowl;
        float* hp = out + (size_t)grow * DIM + n0 + ch;
        if (hasL[rowl]) {
            const float mu = muL[rowl], inv = invL[rowl];
#pragma unroll 4
            for (int it = 0; it < 16; ++it) {
                floatx4 hv = *reinterpret_cast<const floatx4*>(hp + it * 4);
                floatx4 gv = *reinterpret_cast<const floatx4*>(g + n0 + ch + it * 4);
                floatx4 bv = *reinterpret_cast<const floatx4*>(b + n0 + ch + it * 4);
                floatx4 o;
#pragma unroll
                for (int e = 0; e < 4; ++e)
                    o[e] = fmaxf((hv[e] - mu) * inv * gv[e] + bv[e], 0.f);
                *reinterpret_cast<floatx4*>(hp + it * 4) = o;
            }
        } else {
            int pr = pos[grow * 2 + 0]; pr = min(max(pr, 0), 99);
            int pc = pos[grow * 2 + 1]; pc = min(max(pc, 0), 99);
            const float* cep = ce + (size_t)grow * DIM + n0 + ch;
            const float* rep = re + (size_t)pr * DIM + n0 + ch;
            const float* cop = co + (size_t)pc * DIM + n0 + ch;
#pragma unroll 4
            for (int it = 0; it < 16; ++it) {
                floatx4 a0 = *reinterpret_cast<const floatx4*>(cep + it * 4);
                floatx4 b0 = *reinterpret_cast<const floatx4*>(rep + it * 4);
                floatx4 c0 = *reinterpret_cast<const floatx4*>(cop + it * 4);
                floatx4 o;
#pragma unroll
                for (int e = 0; e < 4; ++e) o[e] = a0[e] + b0[e] + c0[e];
                *reinterpret_cast<floatx4*>(hp + it * 4) = o;
            }
        }
    }
}

// ===========================================================================
// PREP kernel: one dispatch replaces 7 logical ops. GEMM blocks FIRST.
//   [0, 192)     HKV  = hdr @ [Wk;Wv]^T + bias
//   [192, 336)   Wco  = Wf2 @ out_w -> Wf_b[:, 768:1536]
//   [336, 339)   bco  = fus_b + Wf2 @ out_b   (+ ctr reset, b==336 tid==0)
//   [339, 915)   Wq_b = bf16(in_proj_w[0:768*768])
//   [915, 1491)  Wf_b[:, 0:768] = bf16(fus_w[:, 0:768])
//   [1491, 7635) cwp_b = bf16(ce + re[pr] + co[pc])
// ===========================================================================
__global__ __launch_bounds__(256) void prep_kernel(
    const float* __restrict__ ce, const int* __restrict__ pos,
    const float* __restrict__ re, const float* __restrict__ co,
    bf16* __restrict__ cwp_b,
    const float* __restrict__ in_proj_w, bf16* __restrict__ Wq_b,
    const float* __restrict__ fus_w,     bf16* __restrict__ Wf_b,
    const float* __restrict__ out_w, const float* __restrict__ out_b,
    const float* __restrict__ fus_b, float* __restrict__ bco,
    const float* __restrict__ hdr, const float* __restrict__ in_proj_b,
    bf16* __restrict__ HKV, int* __restrict__ ctr)
{
    __shared__ short As[64 * 72];   // GEMM branches only (9,216 B each)
    __shared__ short Bs[64 * 72];
    const int b = blockIdx.x, tid = threadIdx.x;

    if (b < 192) {                           // ---- HKV GEMM (BK=64, reg-prefetch) ----
        const int m0 = (b & 7) * 64, n0 = (b >> 3) * 64;
        const float* W = in_proj_w + (size_t)DIM * DIM;   // [Wk;Wv]
        const float* bias = in_proj_b + DIM;
        const int wave = tid >> 6, lane = tid & 63;
        const int lr = tid >> 2, lc = (tid & 3) * 16;
        const int fr = lane & 15, fk = (lane >> 4) * 8;

        floatx4 acc[4];
#pragma unroll
        for (int i = 0; i < 4; ++i) acc[i] = (floatx4){0.f, 0.f, 0.f, 0.f};

        const float* ap = hdr + (size_t)(m0 + lr) * DIM + lc;
        const float* wp = W   + (size_t)(n0 + lr) * DIM + lc;
        short8 a0 = ld8(ap), a1 = ld8(ap + 8);
        short8 w0 = ld8(wp), w1 = ld8(wp + 8);

        for (int it = 0; it < 12; ++it) {
            __syncthreads();
            *reinterpret_cast<short8*>(&As[lr * 72 + lc])     = a0;
            *reinterpret_cast<short8*>(&As[lr * 72 + lc + 8]) = a1;
            *reinterpret_cast<short8*>(&Bs[lr * 72 + lc])     = w0;
            *reinterpret_cast<short8*>(&Bs[lr * 72 + lc + 8]) = w1;
            __syncthreads();
            if (it < 11) {
                const int k0 = (it + 1) * 64;
                a0 = ld8(ap + k0); a1 = ld8(ap + k0 + 8);
                w0 = ld8(wp + k0); w1 = ld8(wp + k0 + 8);
            }
#pragma unroll
            for (int kk = 0; kk < 2; ++kk) {
                short8 af = *reinterpret_cast<const short8*>(
                    &As[(wave * 16 + fr) * 72 + kk * 32 + fk]);
#pragma unroll
                for (int t = 0; t < 4; ++t) {
                    short8 bfv = *reinterpret_cast<const short8*>(
                        &Bs[(t * 16 + fr) * 72 + kk * 32 + fk]);
                    acc[t] = __builtin_amdgcn_mfma_f32_16x16x32_bf16(af, bfv, acc[t], 0, 0, 0);
                }
            }
        }
        const int col_l = lane & 15, row_q = (lane >> 4) * 4;
#pragma unroll
        for (int t = 0; t < 4; ++t) {
            const int col = n0 + t * 16 + col_l;
            const float bv = bias[col];
#pragma unroll
            for (int r = 0; r < 4; ++r) {
                const int row = m0 + wave * 16 + row_q + r;
                HKV[(size_t)row * 1536 + col] = __float2bfloat16(acc[t][r] + bv);
            }
        }
    } else if (b < 336) {                    // ---- Wco = Wf2 @ out_w ----
        const int b3 = b - 192;
        const int n0  = (b3 % 12) * 64;
        const int k0t = (b3 / 12) * 64;
        const int wave = tid >> 6, lane = tid & 63;
        const int lr = tid >> 2, lc = (tid & 3) * 16;
        const int fr = lane & 15, fk = (lane >> 4) * 8;

        floatx4 acc[4];
#pragma unroll
        for (int i = 0; i < 4; ++i) acc[i] = (floatx4){0.f, 0.f, 0.f, 0.f};

        const float* ap = fus_w + (size_t)(n0 + lr) * 1536 + 768 + lc;
        const float* bp = out_w + (size_t)lr * DIM + k0t + lc;
        short8 a0 = ld8(ap), a1 = ld8(ap + 8);
        floatx4 q0 = *reinterpret_cast<const floatx4*>(bp);
        floatx4 q1 = *reinterpret_cast<const floatx4*>(bp + 4);
        floatx4 q2 = *reinterpret_cast<const floatx4*>(bp + 8);
        floatx4 q3 = *reinterpret_cast<const floatx4*>(bp + 12);

        for (int it = 0; it < 12; ++it) {
            __syncthreads();
            *reinterpret_cast<short8*>(&As[lr * 72 + lc])     = a0;
            *reinterpret_cast<short8*>(&As[lr * 72 + lc + 8]) = a1;
#pragma unroll
            for (int e = 0; e < 4; ++e) {    // transpose out_w tile: Bs[col][r]
                Bs[(lc + e) * 72 + lr]      = f2b(q0[e]);
                Bs[(lc + 4 + e) * 72 + lr]  = f2b(q1[e]);
                Bs[(lc + 8 + e) * 72 + lr]  = f2b(q2[e]);
                Bs[(lc + 12 + e) * 72 + lr] = f2b(q3[e]);
            }
            __syncthreads();
            if (it < 11) {
                const int r0 = (it + 1) * 64;
                a0 = ld8(ap + r0); a1 = ld8(ap + r0 + 8);
                const float* bq = bp + (size_t)r0 * DIM;
                q0 = *reinterpret_cast<const floatx4*>(bq);
                q1 = *reinterpret_cast<const floatx4*>(bq + 4);
                q2 = *reinterpret_cast<const floatx4*>(bq + 8);
                q3 = *reinterpret_cast<const floatx4*>(bq + 12);
            }
#pragma unroll
            for (int kk = 0; kk < 2; ++kk) {
                short8 af = *reinterpret_cast<const short8*>(
                    &As[(wave * 16 + fr) * 72 + kk * 32 + fk]);
#pragma unroll
                for (int t = 0; t < 4; ++t) {
                    short8 bfv = *reinterpret_cast<const short8*>(
                        &Bs[(t * 16 + fr) * 72 + kk * 32 + fk]);
                    acc[t] = __builtin_amdgcn_mfma_f32_16x16x32_bf16(af, bfv, acc[t], 0, 0, 0);
                }
            }
        }
        const int col_l = lane & 15, row_q = (lane >> 4) * 4;
#pragma unroll
        for (int t = 0; t < 4; ++t) {
            const int col = k0t + t * 16 + col_l;
#pragma unroll
            for (int r = 0; r < 4; ++r) {
                const int row = n0 + wave * 16 + row_q + r;
                Wf_b[(size_t)row * 1536 + 768 + col] = __float2bfloat16(acc[t][r]);
            }
        }
    } else if (b < 339) {                    // ---- bco + ctr reset ----
        if (b == 336 && tid == 0) *ctr = 0;   // grid-barrier counter reset
        const int n = (b - 336) * 256 + tid;
        const float* wrow = fus_w + (size_t)n * 1536 + 768;
        float acc = fus_b[n];
#pragma unroll 4
        for (int m = 0; m < 768; m += 4) {
            floatx4 wv = *reinterpret_cast<const floatx4*>(wrow + m);
            floatx4 ob = *reinterpret_cast<const floatx4*>(out_b + m);
            acc += wv[0] * ob[0] + wv[1] * ob[1] + wv[2] * ob[2] + wv[3] * ob[3];
        }
        bco[n] = acc;
    } else if (b < 915) {                    // ---- Wq convert ----
        const int i = (b - 339) * 256 + tid;
        floatx4 v = *reinterpret_cast<const floatx4*>(in_proj_w + (size_t)i * 4);
        short4v o;
#pragma unroll
        for (int j = 0; j < 4; ++j) o[j] = f2b(v[j]);
        *reinterpret_cast<short4v*>((short*)Wq_b + (size_t)i * 4) = o;
    } else if (b < 1491) {                   // ---- Wf1 convert (cols 0:768) ----
        const int i  = (b - 915) * 256 + tid;
        const int e0 = i * 4;
        const int n  = e0 / 768;
        const int k  = e0 - n * 768;
        const size_t src = (size_t)n * 1536 + k;
        floatx4 v = *reinterpret_cast<const floatx4*>(fus_w + src);
        short4v o;
#pragma unroll
        for (int j = 0; j < 4; ++j) o[j] = f2b(v[j]);
        *reinterpret_cast<short4v*>((short*)Wf_b + src) = o;
    } else {                                 // ---- cwp_b ----
        const int gid  = (b - 1491) * 256 + tid;
        const int cell = gid / 96;
        const int off  = (gid % 96) * 8;
        int pr = pos[cell * 2 + 0]; pr = min(max(pr, 0), 99);
        int pc = pos[cell * 2 + 1]; pc = min(max(pc, 0), 99);
        const float* a = ce + (size_t)cell * DIM + off;
        const float* bb = re + (size_t)pr * DIM + off;
        const float* c = co + (size_t)pc * DIM + off;
        floatx4 a0 = *reinterpret_cast<const floatx4*>(a);
        floatx4 a1 = *reinterpret_cast<const floatx4*>(a + 4);
        floatx4 b0 = *reinterpret_cast<const floatx4*>(bb);
        floatx4 b1 = *reinterpret_cast<const floatx4*>(bb + 4);
        floatx4 c0 = *reinterpret_cast<const floatx4*>(c);
        floatx4 c1 = *reinterpret_cast<const floatx4*>(c + 4);
        short8 o;
#pragma unroll
        for (int i = 0; i < 4; ++i) {
            o[i]     = f2b(a0[i] + b0[i] + c0[i]);
            o[i + 4] = f2b(a1[i] + b1[i] + c1[i]);
        }
        *reinterpret_cast<short8*>((short*)cwp_b + (size_t)cell * DIM + off) = o;
    }
}

// ---------------------------------------------------------------------------
// LDS-staged attention (R4, verified): 2 cells per 256-thr block. K-rows
// staged into LDS via coalesced global_load_lds with source-granule XOR
// swizzle; V register prefetch rides under score compute. Two barriers.
// ---------------------------------------------------------------------------
__global__ __launch_bounds__(256) void attn_l_kernel(
    const bf16* __restrict__ q, bf16* __restrict__ ctx,
    const bf16* __restrict__ HKV, const int* __restrict__ map,
    float* __restrict__ wout)
{
    const int h = threadIdx.x >> 7;
    const int t = threadIdx.x & 127;
    const int cell = blockIdx.x * 2 + h;

    __shared__ short Ks[2][8 * 768];
    __shared__ int   ids[2][MAXH];
    __shared__ float msk[2][MAXH];
    __shared__ float at_l[2][64];

    if (t < MAXH) {
        int id = map[(size_t)cell * MAXH + t];
        msk[h][t] = (id >= 0) ? 1.f : 0.f;
        ids[h][t] = (id >= 0) ? id : 0;
    }

    const int a = t >> 3, j = t & 7;
    short8 qv[12];
    if (t < 64) {
        const short* qp = (const short*)q + (size_t)cell * DIM + a * DHEAD;
#pragma unroll
        for (int c = 0; c < 12; ++c)
            qv[c] = *reinterpret_cast<const short8*>(qp + c * 8);
    }

#pragma unroll
    for (int s = 0; s < 6; ++s) {
        const int P  = s * 128 + t;
        const int jr = P / 96;
        const int gi = (P - jr * 96) ^ (jr & 7);
        int id = map[(size_t)cell * MAXH + jr];
        id = (id >= 0) ? id : 0;
        cp16((const short*)HKV + (size_t)id * 1536 + gi * 8, &Ks[h][P * 8]);
    }
    __syncthreads();

    short8 vv[8];
    if (t < 96) {
        const int d0 = t * 8;
#pragma unroll
        for (int jj = 0; jj < 8; ++jj)
            vv[jj] = *reinterpret_cast<const short8*>(
                (const short*)HKV + (size_t)ids[h][jj] * 1536 + DIM + d0);
    }

    if (t < 64) {
        float s0 = 0.f, s1 = 0.f, s2 = 0.f, s3 = 0.f;
#pragma unroll
        for (int cc = 0; cc < 12; cc += 4) {
            short8 kv[4];
#pragma unroll
            for (int u = 0; u < 4; ++u) {
                const int gi = (a * 12 + cc + u) ^ (j & 7);
                kv[u] = *reinterpret_cast<const short8*>(&Ks[h][(j * 96 + gi) * 8]);
            }
#pragma unroll
            for (int e = 0; e < 8; ++e) {
                s0 += b2f(qv[cc    ][e]) * b2f(kv[0][e]);
                s1 += b2f(qv[cc + 1][e]) * b2f(kv[1][e]);
                s2 += b2f(qv[cc + 2][e]) * b2f(kv[2][e]);
                s3 += b2f(qv[cc + 3][e]) * b2f(kv[3][e]);
            }
        }
        float s = ((s0 + s1) + (s2 + s3)) * 0.10206207261596577f;
        const float mk = msk[h][j];
        s = (mk != 0.f) ? s : -1e9f;
        float m = s;
        m = fmaxf(m, __shfl_xor(m, 1));
        m = fmaxf(m, __shfl_xor(m, 2));
        m = fmaxf(m, __shfl_xor(m, 4));
        float e = expf(s - m) * mk;
        float sum = e;
        sum += __shfl_xor(sum, 1);
        sum += __shfl_xor(sum, 2);
        sum += __shfl_xor(sum, 4);
        at_l[h][t] = (sum > 0.f) ? e / sum : 0.f;
    }
    __syncthreads();

    if (t < 96) {
        const int d0 = t * 8, ha = t / 12;
        float w[8];
#pragma unroll
        for (int jj = 0; jj < 8; ++jj) w[jj] = at_l[h][ha * 8 + jj];
        float acc[8];
#pragma unroll
        for (int e = 0; e < 8; ++e) acc[e] = 0.f;
#pragma unroll
        for (int jj = 0; jj < 8; ++jj)
#pragma unroll
            for (int e = 0; e < 8; ++e) acc[e] += w[jj] * b2f(vv[jj][e]);
        short8 o;
#pragma unroll
        for (int e = 0; e < 8; ++e) o[e] = f2b(acc[e]);
        *reinterpret_cast<short8*>((short*)ctx + (size_t)cell * DIM + d0) = o;
    } else if (t < 96 + MAXH) {
        const int jj = t - 96;
        float s = 0.f;
#pragma unroll
        for (int a2 = 0; a2 < NHEADS; ++a2) s += at_l[h][a2 * 8 + jj];
        wout[(size_t)cell * MAXH + jj] = s * 0.125f;
    }
}

// ---------------------------------------------------------------------------
extern "C" void kernel_launch(void* const* d_in, const int* in_sizes, int n_in,
                              void* d_out, int out_size, void* d_ws, size_t ws_size,
                              hipStream_t stream) {
    (void)in_sizes; (void)n_in; (void)out_size; (void)ws_size;

    const float* cell_emb  = (const float*)d_in[0];
    const float* hdr_emb   = (const float*)d_in[1];
    const int*   map       = (const int*)d_in[2];
    const int*   pos       = (const int*)d_in[3];
    const float* in_proj_w = (const float*)d_in[4];   // [2304, 768]
    const float* in_proj_b = (const float*)d_in[5];
    const float* out_w     = (const float*)d_in[6];   // [768, 768]
    const float* out_b     = (const float*)d_in[7];
    const float* row_emb   = (const float*)d_in[8];
    const float* col_emb   = (const float*)d_in[9];
    const float* fus_w     = (const float*)d_in[10];  // [768, 1536]
    const float* fus_b     = (const float*)d_in[11];
    const float* ln_g      = (const float*)d_in[12];
    const float* ln_b      = (const float*)d_in[13];
    float* out = (float*)d_out;

    // ws layout (bytes) — total 56,623,104 (R4-proven):
    //   HKV   bf16 [512,1536]  @ 0          ( 1,572,864)
    //   ctx_b bf16 [16384,768] @ 1572864    (25,165,824)
    //   cwp_b bf16 [16384,768] @ 26738688   (25,165,824)
    //   Wq_b  bf16 [768,768]   @ 51904512   ( 1,179,648)  -> Sg scratch after qproj
    //   bco   f32  [768]       @ 53084160   (     3,072)
    //   ctr   int              @ 53087232   (         4)
    //   Wf_b  bf16 [768,1536]  @ 54263808   ( 2,359,296)  [Wf1 | Wco]
    char* ws = (char*)d_ws;
    bf16*  HKV   = (bf16*)ws;
    bf16*  ctx_b = (bf16*)(ws + 1572864);
    bf16*  cwp_b = (bf16*)(ws + 26738688);
    bf16*  Wq_b  = (bf16*)(ws + 51904512);
    float* Sg    = (float*)(ws + 51904512);   // 786,432 B, reuses dead Wq_b
    float* bco   = (float*)(ws + 53084160);
    int*   ctr   = (int*)(ws + 53087232);
    bf16*  Wf_b  = (bf16*)(ws + 54263808);
    // d_out raw-byte scratch: q_b bf16 @ [0,25165824) — dead before fusion
    bf16* q_b = (bf16*)d_out;

    // 1. PREP: HKV + Wco GEMMs first (overlap tail), then converts + cwp
    prep_kernel<<<7635, 256, 0, stream>>>(
        cell_emb, pos, row_emb, col_emb, cwp_b,
        in_proj_w, Wq_b, fus_w, Wf_b,
        out_w, out_b, fus_b, bco,
        hdr_emb, in_proj_b, HKV, ctr);

    // 2. q_b = cwp_b @ Wq_b^T + bq  (bf16 out -> d_out bytes [0,25MB))
    gemm_bf<0, 1><<<768, 256, 0, stream>>>(
        cwp_b, nullptr, Wq_b, DIM, in_proj_b, nullptr, q_b, DIM);

    // 3. attention: q_b -> ctx_b (ws); weights -> d_out tail (fp32)
    attn_l_kernel<<<NCELLS / 2, 256, 0, stream>>>(q_b, ctx_b, HKV, map, out + ND);

    // 4. FUSED (regular launch + software grid barrier, no acc across barrier):
    //    h = [cwp|ctx]@[Wf1|Wco]^T + bco -> out (fp32, R8 pattern), barrier,
    //    LN+ReLU+select on own L2-hot tile. ln dispatch eliminated.
    fusion_ln_sync<<<768, 256, 0, stream>>>(
        cwp_b, ctx_b, Wf_b, bco, out, Sg, ctr, map,
        cell_emb, pos, row_emb, col_emb, ln_g, ln_b);
}

// Round 12
// 284.141 us; speedup vs baseline: 1.5098x; 1.5098x over previous
//
#include <hip/hip_runtime.h>
#include <hip/hip_bf16.h>

// Problem constants (fixed by reference)
#define NCELLS 16384
#define DIM    768
#define NHEADS 8
#define DHEAD  96           // 768/8
#define MAXH   8
#define ND     (NCELLS * DIM)          // 12582912

// ALL float tensors are fp32 I/O (reference uses jnp.float32 throughout).
// Internal compute: bf16 operands + MFMA, fp32 accumulate/output.

using bf16 = __hip_bfloat16;
typedef short  short8  __attribute__((ext_vector_type(8)));
typedef short  short4v __attribute__((ext_vector_type(4)));
typedef float  floatx4 __attribute__((ext_vector_type(4)));

__device__ inline short f2b(float f) {
    bf16 h = __float2bfloat16(f);
    unsigned short u; __builtin_memcpy(&u, &h, 2); return (short)u;
}
__device__ inline float b2f(short u) {
    unsigned x = ((unsigned)(unsigned short)u) << 16;
    float f; __builtin_memcpy(&f, &x, 4); return f;
}

// load 8 consecutive fp32, convert to 8 bf16
__device__ inline short8 ld8(const float* p) {
    floatx4 a = *reinterpret_cast<const floatx4*>(p);
    floatx4 b = *reinterpret_cast<const floatx4*>(p + 4);
    short8 o;
#pragma unroll
    for (int i = 0; i < 4; ++i) { o[i] = f2b(a[i]); o[i + 4] = f2b(b[i]); }
    return o;
}

// async 16B global -> LDS (direct DMA, no VGPR round-trip). Destination is
// wave-uniform base + lane*16 (m104/m108): pass per-lane addr; lane0 = base.
__device__ __forceinline__ void cp16(const void* g, void* l) {
    __builtin_amdgcn_global_load_lds(
        (const __attribute__((address_space(1))) void*)g,
        (__attribute__((address_space(3))) void*)l, 16, 0, 0);
}

// ===========================================================================
// Pure-bf16 GEMM, 128x128 tile, BK=64, 256 thr (4 waves, 2x2), staging via
// global_load_lds width=16. XCD-swizzled linear grid: mb=id&127, nb=id>>7.
// LDS tiles UNPADDED [128][64]; bank conflicts broken by XOR-swizzling the
// k-group with row&7 on the GLOBAL source address + matching XOR on ds_read.
// Measured: 0 bank conflicts, fusion (K=1536) ~53 us (~730 TF) — at the
// m97 2-barrier-structure ceiling (R8 verified, 285.4 us total).
// DUAL=1: A spans K=1536 as [A | A2]. COUT: 0=f32 C, 1=bf16 C.
// ===========================================================================
template <int DUAL, int COUT>
__global__ __launch_bounds__(256) void gemm_bf(
    const bf16* __restrict__ A, const bf16* __restrict__ A2,
    const bf16* __restrict__ W, int ldw,
    const float* __restrict__ bias,
    float* __restrict__ Cf, bf16* __restrict__ Cb, int K)
{
    __shared__ short As[128 * 64];   // 16,384 B
    __shared__ short Bs[128 * 64];   // 16,384 B
    const int tid = threadIdx.x, wave = tid >> 6, lane = tid & 63;
    const int id = blockIdx.x;
    const int m0 = (id & 127) * 128;
    const int n0 = (id >> 7) * 128;
    const int wr = (wave & 1) * 64, wc = (wave >> 1) * 64;
    const int fr = lane & 15, kg = lane >> 4;   // fragment row / k-group

    const int srow = lane >> 3;            // row within chunk (== row&7)
    const int scol = (lane & 7) ^ srow;    // swizzled source k-group

    floatx4 acc[16];
#pragma unroll
    for (int i = 0; i < 16; ++i) acc[i] = (floatx4){0.f, 0.f, 0.f, 0.f};

    for (int k0 = 0; k0 < K; k0 += 64) {
        const bf16* Ak; int ka;
        if (!DUAL || k0 < DIM) { Ak = A;  ka = k0; }
        else                   { Ak = A2; ka = k0 - DIM; }

        __syncthreads();   // previous iteration's ds_reads complete
#pragma unroll
        for (int i = 0; i < 4; ++i) {
            const int c = i * 4 + wave;
            const int row = c * 8 + srow;
            cp16(Ak + (size_t)(m0 + row) * DIM + ka + scol * 8,
                 &As[c * 512 + lane * 8]);
            cp16(W  + (size_t)(n0 + row) * ldw + k0 + scol * 8,
                 &Bs[c * 512 + lane * 8]);
        }
        __syncthreads();   // vmcnt(0) drained: tiles landed

#pragma unroll
        for (int kk = 0; kk < 2; ++kk) {
            short8 af[4], bfv[4];
#pragma unroll
            for (int i = 0; i < 4; ++i) {
                const int sa = ((kk * 4 + kg) ^ (fr & 7)) * 8;
                af[i]  = *reinterpret_cast<const short8*>(&As[(wr + i * 16 + fr) * 64 + sa]);
                bfv[i] = *reinterpret_cast<const short8*>(&Bs[(wc + i * 16 + fr) * 64 + sa]);
            }
#pragma unroll
            for (int i = 0; i < 4; ++i)
#pragma unroll
                for (int j = 0; j < 4; ++j)
                    acc[i * 4 + j] = __builtin_amdgcn_mfma_f32_16x16x32_bf16(
                        af[i], bfv[j], acc[i * 4 + j], 0, 0, 0);
        }
    }

    const int col_l = lane & 15, row_q = kg * 4;
#pragma unroll
    for (int j = 0; j < 4; ++j) {
        const int col = n0 + wc + j * 16 + col_l;
        const float bv = bias[col];
#pragma unroll
        for (int i = 0; i < 4; ++i) {
#pragma unroll
            for (int r = 0; r < 4; ++r) {
                const int row = m0 + wr + i * 16 + row_q + r;
                const float v = acc[i * 4 + j][r] + bv;
                if (COUT == 0) Cf[(size_t)row * DIM + col] = v;
                else           Cb[(size_t)row * DIM + col] = __float2bfloat16(v);
            }
        }
    }
}

// ===========================================================================
// PREP kernel: one dispatch replaces 7 logical ops. GEMM blocks FIRST so
// their long tail overlaps the streaming bulk (R1->R2: prep 79 -> <52 us).
//   [0, 192)         HKV  = hdr @ [Wk;Wv]^T + bias (64x64 tile, BK=64)
//   [192, 336)       Wco  = Wf2 @ out_w -> Wf_b[:, 768:1536]
//   [336, 339)       bco  = fus_b + Wf2 @ out_b
//   [339, 915)       Wq_b = bf16(in_proj_w[0:768*768])
//   [915, 1491)      Wf_b[:, 0:768] = bf16(fus_w[:, 0:768])
//   [1491, 7635)     cwp_b = bf16(ce + re[pr] + co[pc])
// ===========================================================================
__global__ __launch_bounds__(256) void prep_kernel(
    const float* __restrict__ ce, const int* __restrict__ pos,
    const float* __restrict__ re, const float* __restrict__ co,
    bf16* __restrict__ cwp_b,
    const float* __restrict__ in_proj_w, bf16* __restrict__ Wq_b,
    const float* __restrict__ fus_w,     bf16* __restrict__ Wf_b,
    const float* __restrict__ out_w, const float* __restrict__ out_b,
    const float* __restrict__ fus_b, float* __restrict__ bco,
    const float* __restrict__ hdr, const float* __restrict__ in_proj_b,
    bf16* __restrict__ HKV)
{
    __shared__ short As[64 * 72];   // GEMM branches only (9,216 B each)
    __shared__ short Bs[64 * 72];
    const int b = blockIdx.x, tid = threadIdx.x;

    if (b < 192) {                           // ---- HKV GEMM (BK=64, reg-prefetch) ----
        const int m0 = (b & 7) * 64, n0 = (b >> 3) * 64;
        const float* W = in_proj_w + (size_t)DIM * DIM;   // [Wk;Wv]
        const float* bias = in_proj_b + DIM;
        const int wave = tid >> 6, lane = tid & 63;
        const int lr = tid >> 2, lc = (tid & 3) * 16;
        const int fr = lane & 15, fk = (lane >> 4) * 8;

        floatx4 acc[4];
#pragma unroll
        for (int i = 0; i < 4; ++i) acc[i] = (floatx4){0.f, 0.f, 0.f, 0.f};

        const float* ap = hdr + (size_t)(m0 + lr) * DIM + lc;
        const float* wp = W   + (size_t)(n0 + lr) * DIM + lc;
        short8 a0 = ld8(ap), a1 = ld8(ap + 8);
        short8 w0 = ld8(wp), w1 = ld8(wp + 8);

        for (int it = 0; it < 12; ++it) {
            __syncthreads();
            *reinterpret_cast<short8*>(&As[lr * 72 + lc])     = a0;
            *reinterpret_cast<short8*>(&As[lr * 72 + lc + 8]) = a1;
            *reinterpret_cast<short8*>(&Bs[lr * 72 + lc])     = w0;
            *reinterpret_cast<short8*>(&Bs[lr * 72 + lc + 8]) = w1;
            __syncthreads();
            if (it < 11) {                   // prefetch next K-tile into regs
                const int k0 = (it + 1) * 64;
                a0 = ld8(ap + k0); a1 = ld8(ap + k0 + 8);
                w0 = ld8(wp + k0); w1 = ld8(wp + k0 + 8);
            }
#pragma unroll
            for (int kk = 0; kk < 2; ++kk) {
                short8 af = *reinterpret_cast<const short8*>(
                    &As[(wave * 16 + fr) * 72 + kk * 32 + fk]);
#pragma unroll
                for (int t = 0; t < 4; ++t) {
                    short8 bfv = *reinterpret_cast<const short8*>(
                        &Bs[(t * 16 + fr) * 72 + kk * 32 + fk]);
                    acc[t] = __builtin_amdgcn_mfma_f32_16x16x32_bf16(af, bfv, acc[t], 0, 0, 0);
                }
            }
        }
        const int col_l = lane & 15, row_q = (lane >> 4) * 4;
#pragma unroll
        for (int t = 0; t < 4; ++t) {
            const int col = n0 + t * 16 + col_l;
            const float bv = bias[col];
#pragma unroll
            for (int r = 0; r < 4; ++r) {
                const int row = m0 + wave * 16 + row_q + r;
                HKV[(size_t)row * 1536 + col] = __float2bfloat16(acc[t][r] + bv);
            }
        }
    } else if (b < 336) {                    // ---- Wco = Wf2 @ out_w ----
        const int b3 = b - 192;
        const int n0  = (b3 % 12) * 64;      // Wco row tile (rows of Wf2)
        const int k0t = (b3 / 12) * 64;      // Wco col tile (cols of out_w)
        const int wave = tid >> 6, lane = tid & 63;
        const int lr = tid >> 2, lc = (tid & 3) * 16;
        const int fr = lane & 15, fk = (lane >> 4) * 8;

        floatx4 acc[4];
#pragma unroll
        for (int i = 0; i < 4; ++i) acc[i] = (floatx4){0.f, 0.f, 0.f, 0.f};

        const float* ap = fus_w + (size_t)(n0 + lr) * 1536 + 768 + lc;  // Wf2 row
        const float* bp = out_w + (size_t)lr * DIM + k0t + lc;          // out_w row r=lr
        short8 a0 = ld8(ap), a1 = ld8(ap + 8);
        floatx4 q0 = *reinterpret_cast<const floatx4*>(bp);
        floatx4 q1 = *reinterpret_cast<const floatx4*>(bp + 4);
        floatx4 q2 = *reinterpret_cast<const floatx4*>(bp + 8);
        floatx4 q3 = *reinterpret_cast<const floatx4*>(bp + 12);

        for (int it = 0; it < 12; ++it) {
            __syncthreads();
            *reinterpret_cast<short8*>(&As[lr * 72 + lc])     = a0;
            *reinterpret_cast<short8*>(&As[lr * 72 + lc + 8]) = a1;
#pragma unroll
            for (int e = 0; e < 4; ++e) {    // transpose out_w tile: Bs[col][r]
                Bs[(lc + e) * 72 + lr]      = f2b(q0[e]);
                Bs[(lc + 4 + e) * 72 + lr]  = f2b(q1[e]);
                Bs[(lc + 8 + e) * 72 + lr]  = f2b(q2[e]);
                Bs[(lc + 12 + e) * 72 + lr] = f2b(q3[e]);
            }
            __syncthreads();
            if (it < 11) {                   // prefetch next r-tile into regs
                const int r0 = (it + 1) * 64;
                a0 = ld8(ap + r0); a1 = ld8(ap + r0 + 8);
                const float* bq = bp + (size_t)r0 * DIM;
                q0 = *reinterpret_cast<const floatx4*>(bq);
                q1 = *reinterpret_cast<const floatx4*>(bq + 4);
                q2 = *reinterpret_cast<const floatx4*>(bq + 8);
                q3 = *reinterpret_cast<const floatx4*>(bq + 12);
            }
#pragma unroll
            for (int kk = 0; kk < 2; ++kk) {
                short8 af = *reinterpret_cast<const short8*>(
                    &As[(wave * 16 + fr) * 72 + kk * 32 + fk]);
#pragma unroll
                for (int t = 0; t < 4; ++t) {
                    short8 bfv = *reinterpret_cast<const short8*>(
                        &Bs[(t * 16 + fr) * 72 + kk * 32 + fk]);
                    acc[t] = __builtin_amdgcn_mfma_f32_16x16x32_bf16(af, bfv, acc[t], 0, 0, 0);
                }
            }
        }
        const int col_l = lane & 15, row_q = (lane >> 4) * 4;
#pragma unroll
        for (int t = 0; t < 4; ++t) {
            const int col = k0t + t * 16 + col_l;
#pragma unroll
            for (int r = 0; r < 4; ++r) {
                const int row = n0 + wave * 16 + row_q + r;
                Wf_b[(size_t)row * 1536 + 768 + col] = __float2bfloat16(acc[t][r]);
            }
        }
    } else if (b < 339) {                    // ---- bco = fus_b + Wf2 @ out_b ----
        const int n = (b - 336) * 256 + tid;   // exactly 768 threads
        const float* wrow = fus_w + (size_t)n * 1536 + 768;
        float acc = fus_b[n];
#pragma unroll 4
        for (int m = 0; m < 768; m += 4) {
            floatx4 wv = *reinterpret_cast<const floatx4*>(wrow + m);
            floatx4 ob = *reinterpret_cast<const floatx4*>(out_b + m);
            acc += wv[0] * ob[0] + wv[1] * ob[1] + wv[2] * ob[2] + wv[3] * ob[3];
        }
        bco[n] = acc;
    } else if (b < 915) {                    // ---- Wq convert ----
        const int i = (b - 339) * 256 + tid;
        floatx4 v = *reinterpret_cast<const floatx4*>(in_proj_w + (size_t)i * 4);
        short4v o;
#pragma unroll
        for (int j = 0; j < 4; ++j) o[j] = f2b(v[j]);
        *reinterpret_cast<short4v*>((short*)Wq_b + (size_t)i * 4) = o;
    } else if (b < 1491) {                   // ---- Wf1 convert (cols 0:768) ----
        const int i  = (b - 915) * 256 + tid;
        const int e0 = i * 4;                // element index within 768x768
        const int n  = e0 / 768;
        const int k  = e0 - n * 768;
        const size_t src = (size_t)n * 1536 + k;
        floatx4 v = *reinterpret_cast<const floatx4*>(fus_w + src);
        short4v o;
#pragma unroll
        for (int j = 0; j < 4; ++j) o[j] = f2b(v[j]);
        *reinterpret_cast<short4v*>((short*)Wf_b + src) = o;
    } else {                                 // ---- cwp_b ----
        const int gid  = (b - 1491) * 256 + tid;
        const int cell = gid / 96;
        const int off  = (gid % 96) * 8;
        int pr = pos[cell * 2 + 0]; pr = min(max(pr, 0), 99);
        int pc = pos[cell * 2 + 1]; pc = min(max(pc, 0), 99);
        const float* a = ce + (size_t)cell * DIM + off;
        const float* bb = re + (size_t)pr * DIM + off;
        const float* c = co + (size_t)pc * DIM + off;
        floatx4 a0 = *reinterpret_cast<const floatx4*>(a);
        floatx4 a1 = *reinterpret_cast<const floatx4*>(a + 4);
        floatx4 b0 = *reinterpret_cast<const floatx4*>(bb);
        floatx4 b1 = *reinterpret_cast<const floatx4*>(bb + 4);
        floatx4 c0 = *reinterpret_cast<const floatx4*>(c);
        floatx4 c1 = *reinterpret_cast<const floatx4*>(c + 4);
        short8 o;
#pragma unroll
        for (int i = 0; i < 4; ++i) {
            o[i]     = f2b(a0[i] + b0[i] + c0[i]);
            o[i + 4] = f2b(a1[i] + b1[i] + c1[i]);
        }
        *reinterpret_cast<short8*>((short*)cwp_b + (size_t)cell * DIM + off) = o;
    }
}

// ---------------------------------------------------------------------------
// LDS-staged attention (R4, verified): 2 cells per 256-thr block. K-rows
// staged into LDS via coalesced global_load_lds with source-granule XOR
// swizzle (linear DMA dest + matching XOR on read — both-sides rule); V
// register prefetch rides under score compute. Two barriers total.
// ---------------------------------------------------------------------------
__global__ __launch_bounds__(256) void attn_l_kernel(
    const bf16* __restrict__ q, bf16* __restrict__ ctx,
    const bf16* __restrict__ HKV, const int* __restrict__ map,
    float* __restrict__ wout)
{
    const int h = threadIdx.x >> 7;           // half-block = cell slot 0/1
    const int t = threadIdx.x & 127;          // lane within half
    const int cell = blockIdx.x * 2 + h;

    __shared__ short Ks[2][8 * 768];          // 12,288 B per cell (swizzled)
    __shared__ int   ids[2][MAXH];
    __shared__ float msk[2][MAXH];
    __shared__ float at_l[2][64];

    if (t < MAXH) {
        int id = map[(size_t)cell * MAXH + t];
        msk[h][t] = (id >= 0) ? 1.f : 0.f;
        ids[h][t] = (id >= 0) ? id : 0;
    }

    // q loads up-front (t<64): independent of LDS staging
    const int a = t >> 3, j = t & 7;          // score coords (valid t<64)
    short8 qv[12];
    if (t < 64) {
        const short* qp = (const short*)q + (size_t)cell * DIM + a * DHEAD;
#pragma unroll
        for (int c = 0; c < 12; ++c)
            qv[c] = *reinterpret_cast<const short8*>(qp + c * 8);
    }

    // stage K rows (8 x 1536 B) into LDS, coalesced DMA, source-swizzled:
    // logical 16B-granule (row jr, gi) stored at phys P = jr*96 + (gi^(jr&7))
#pragma unroll
    for (int s = 0; s < 6; ++s) {
        const int P  = s * 128 + t;
        const int jr = P / 96;
        const int gi = (P - jr * 96) ^ (jr & 7);
        int id = map[(size_t)cell * MAXH + jr];
        id = (id >= 0) ? id : 0;
        cp16((const short*)HKV + (size_t)id * 1536 + gi * 8, &Ks[h][P * 8]);
    }
    __syncthreads();   // staging landed (__syncthreads drains vmcnt)

    // V prefetch into registers (coalesced); stays in flight under scores
    short8 vv[8];
    if (t < 96) {
        const int d0 = t * 8;
#pragma unroll
        for (int jj = 0; jj < 8; ++jj)
            vv[jj] = *reinterpret_cast<const short8*>(
                (const short*)HKV + (size_t)ids[h][jj] * 1536 + DIM + d0);
    }

    if (t < 64) {                             // ---- scores from LDS K ----
        float s0 = 0.f, s1 = 0.f, s2 = 0.f, s3 = 0.f;
#pragma unroll
        for (int cc = 0; cc < 12; cc += 4) {
            short8 kv[4];
#pragma unroll
            for (int u = 0; u < 4; ++u) {
                const int gi = (a * 12 + cc + u) ^ (j & 7);   // matching XOR
                kv[u] = *reinterpret_cast<const short8*>(&Ks[h][(j * 96 + gi) * 8]);
            }
#pragma unroll
            for (int e = 0; e < 8; ++e) {
                s0 += b2f(qv[cc    ][e]) * b2f(kv[0][e]);
                s1 += b2f(qv[cc + 1][e]) * b2f(kv[1][e]);
                s2 += b2f(qv[cc + 2][e]) * b2f(kv[2][e]);
                s3 += b2f(qv[cc + 3][e]) * b2f(kv[3][e]);
            }
        }
        float s = ((s0 + s1) + (s2 + s3)) * 0.10206207261596577f;  // 1/sqrt(96)
        const float mk = msk[h][j];
        s = (mk != 0.f) ? s : -1e9f;
        float m = s;
        m = fmaxf(m, __shfl_xor(m, 1));
        m = fmaxf(m, __shfl_xor(m, 2));
        m = fmaxf(m, __shfl_xor(m, 4));
        float e = expf(s - m) * mk;           // exact 0 on masked slots
        float sum = e;
        sum += __shfl_xor(sum, 1);
        sum += __shfl_xor(sum, 2);
        sum += __shfl_xor(sum, 4);
        at_l[h][t] = (sum > 0.f) ? e / sum : 0.f;   // all-masked -> 0
    }
    __syncthreads();

    if (t < 96) {                             // ---- ctx from prefetched vv ----
        const int d0 = t * 8, ha = t / 12;
        float w[8];
#pragma unroll
        for (int jj = 0; jj < 8; ++jj) w[jj] = at_l[h][ha * 8 + jj];
        float acc[8];
#pragma unroll
        for (int e = 0; e < 8; ++e) acc[e] = 0.f;
#pragma unroll
        for (int jj = 0; jj < 8; ++jj)
#pragma unroll
            for (int e = 0; e < 8; ++e) acc[e] += w[jj] * b2f(vv[jj][e]);
        short8 o;
#pragma unroll
        for (int e = 0; e < 8; ++e) o[e] = f2b(acc[e]);
        *reinterpret_cast<short8*>((short*)ctx + (size_t)cell * DIM + d0) = o;
    } else if (t < 96 + MAXH) {               // ---- head-averaged weights ----
        const int jj = t - 96;
        float s = 0.f;
#pragma unroll
        for (int a2 = 0; a2 < NHEADS; ++a2) s += at_l[h][a2 * 8 + jj];
        wout[(size_t)cell * MAXH + jj] = s * 0.125f;
    }
}

// ---------------------------------------------------------------------------
// LayerNorm + ReLU + has-select, IN-PLACE, vectorized; 2 cells per 384-thr
// block (three waves per cell; halves are wave-aligned: 192 = 3 x 64).
// ---------------------------------------------------------------------------
__global__ __launch_bounds__(384) void ln_v_kernel(
    float* io, const int* __restrict__ map,
    const float* __restrict__ ce, const int* __restrict__ pos,
    const float* __restrict__ re, const float* __restrict__ co,
    const float* __restrict__ g, const float* __restrict__ b)
{
    const int h = threadIdx.x / 192;          // half 0/1
    const int t = threadIdx.x % 192;
    const int cell = blockIdx.x * 2 + h;
    const int wave = t >> 6, lane = t & 63;
    __shared__ float ws_[2][3], wq_[2][3];
    __shared__ int hasf[2];
    if (threadIdx.x < 2) hasf[threadIdx.x] = 0;

    float* hp = io + (size_t)cell * DIM;
    floatx4 v = *reinterpret_cast<const floatx4*>(hp + t * 4);
    float s  = v[0] + v[1] + v[2] + v[3];
    float q2 = v[0]*v[0] + v[1]*v[1] + v[2]*v[2] + v[3]*v[3];
#pragma unroll
    for (int off = 32; off > 0; off >>= 1) {
        s  += __shfl_down(s, off);
        q2 += __shfl_down(q2, off);
    }
    __syncthreads();           // hasf init visible
    if (t < MAXH && map[cell * MAXH + t] >= 0) hasf[h] = 1;
    if (lane == 0) { ws_[h][wave] = s; wq_[h][wave] = q2; }
    __syncthreads();

    const float mu  = (ws_[h][0] + ws_[h][1] + ws_[h][2]) * (1.f / 768.f);
    const float var = (wq_[h][0] + wq_[h][1] + wq_[h][2]) * (1.f / 768.f) - mu * mu;
    const float inv = rsqrtf(var + 1e-5f);

    if (hasf[h]) {
        floatx4 gv = *reinterpret_cast<const floatx4*>(g + t * 4);
        floatx4 bv = *reinterpret_cast<const floatx4*>(b + t * 4);
        floatx4 o;
#pragma unroll
        for (int e = 0; e < 4; ++e)
            o[e] = fmaxf((v[e] - mu) * inv * gv[e] + bv[e], 0.f);
        *reinterpret_cast<floatx4*>(hp + t * 4) = o;
    } else {
        int pr = pos[cell * 2 + 0]; pr = min(max(pr, 0), 99);
        int pc = pos[cell * 2 + 1]; pc = min(max(pc, 0), 99);
        floatx4 a0 = *reinterpret_cast<const floatx4*>(ce + (size_t)cell * DIM + t * 4);
        floatx4 b0 = *reinterpret_cast<const floatx4*>(re + (size_t)pr * DIM + t * 4);
        floatx4 c0 = *reinterpret_cast<const floatx4*>(co + (size_t)pc * DIM + t * 4);
        floatx4 o;
#pragma unroll
        for (int e = 0; e < 4; ++e) o[e] = a0[e] + b0[e] + c0[e];
        *reinterpret_cast<floatx4*>(hp + t * 4) = o;
    }
}

// ---------------------------------------------------------------------------
extern "C" void kernel_launch(void* const* d_in, const int* in_sizes, int n_in,
                              void* d_out, int out_size, void* d_ws, size_t ws_size,
                              hipStream_t stream) {
    (void)in_sizes; (void)n_in; (void)out_size; (void)ws_size;

    const float* cell_emb  = (const float*)d_in[0];
    const float* hdr_emb   = (const float*)d_in[1];
    const int*   map       = (const int*)d_in[2];
    const int*   pos       = (const int*)d_in[3];
    const float* in_proj_w = (const float*)d_in[4];   // [2304, 768]
    const float* in_proj_b = (const float*)d_in[5];
    const float* out_w     = (const float*)d_in[6];   // [768, 768]
    const float* out_b     = (const float*)d_in[7];
    const float* row_emb   = (const float*)d_in[8];
    const float* col_emb   = (const float*)d_in[9];
    const float* fus_w     = (const float*)d_in[10];  // [768, 1536]
    const float* fus_b     = (const float*)d_in[11];
    const float* ln_g      = (const float*)d_in[12];
    const float* ln_b      = (const float*)d_in[13];
    float* out = (float*)d_out;

    // ws layout (bytes) — total 56,623,104 (R4/R8-proven):
    //   HKV   bf16 [512,1536]  @ 0          ( 1,572,864)
    //   ctx_b bf16 [16384,768] @ 1572864    (25,165,824)
    //   cwp_b bf16 [16384,768] @ 26738688   (25,165,824)
    //   Wq_b  bf16 [768,768]   @ 51904512   ( 1,179,648)
    //   bco   f32  [768]       @ 53084160   (     3,072)
    //   Wf_b  bf16 [768,1536]  @ 54263808   ( 2,359,296)  [Wf1 | Wco]
    char* ws = (char*)d_ws;
    bf16*  HKV   = (bf16*)ws;
    bf16*  ctx_b = (bf16*)(ws + 1572864);
    bf16*  cwp_b = (bf16*)(ws + 26738688);
    bf16*  Wq_b  = (bf16*)(ws + 51904512);
    float* bco   = (float*)(ws + 53084160);
    bf16*  Wf_b  = (bf16*)(ws + 54263808);
    // d_out raw-byte scratch: q_b bf16 @ [0,25165824) — dead before fusion GEMM
    bf16* q_b = (bf16*)d_out;

    // 1. PREP: HKV + Wco GEMMs first (overlap tail), then converts + cwp
    prep_kernel<<<7635, 256, 0, stream>>>(
        cell_emb, pos, row_emb, col_emb, cwp_b,
        in_proj_w, Wq_b, fus_w, Wf_b,
        out_w, out_b, fus_b, bco,
        hdr_emb, in_proj_b, HKV);

    // 2. q_b = cwp_b @ Wq_b^T + bq  (bf16 out -> d_out bytes [0,25MB))
    gemm_bf<0, 1><<<768, 256, 0, stream>>>(
        cwp_b, nullptr, Wq_b, DIM, in_proj_b, nullptr, q_b, DIM);

    // 3. attention: q_b -> ctx_b (ws); weights -> d_out tail (fp32)
    attn_l_kernel<<<NCELLS / 2, 256, 0, stream>>>(q_b, ctx_b, HKV, map, out + ND);

    // 4. h = [cwp_b | ctx_b] @ [Wf1 | Wco]^T + bco  (fp32 out -> d_out)
    //    (out-projection folded: ctx@(Wf2@Wo)^T == (ctx@Wo^T)@Wf2^T)
    gemm_bf<1, 0><<<768, 256, 0, stream>>>(
        cwp_b, ctx_b, Wf_b, 1536, bco, out, nullptr, 1536);

    // 5. LayerNorm + ReLU + select (in-place on d_out fp32)
    ln_v_kernel<<<NCELLS / 2, 384, 0, stream>>>(out, map, cell_emb, pos,
                                                row_emb, col_emb, ln_g, ln_b);
}